// Round 8
// baseline (6039.079 us; speedup 1.0000x reference)
//
#include <hip/hip_runtime.h>
#include <float.h>

#define N_PTS 16384
#define M_PTS 4096
#define K_NN  16
#define CIN   64
#define COUT  64

typedef float v2f __attribute__((ext_vector_type(2)));
typedef unsigned long long ull;

// Exact f32 rounding to match numpy/jax: ((dx*dx + dy*dy) + dz*dz), no fma contraction.
__device__ __forceinline__ float dist2_exact(float ax, float ay, float az,
                                             float bx, float by, float bz) {
    float dx = __fsub_rn(ax, bx);
    float dy = __fsub_rn(ay, by);
    float dz = __fsub_rn(az, bz);
    return __fadd_rn(__fadd_rn(__fmul_rn(dx, dx), __fmul_rn(dy, dy)), __fmul_rn(dz, dz));
}

// Packed f32 ops via inline asm (v2f codegen otherwise scalarizes — R6 evidence).
// pk_add with a pre-negated operand == exact subtraction (negation is exact).
__device__ __forceinline__ v2f pk_add(v2f a, v2f b) {
    v2f d; asm("v_pk_add_f32 %0, %1, %2" : "=v"(d) : "v"(a), "v"(b)); return d;
}
__device__ __forceinline__ v2f pk_mul(v2f a, v2f b) {
    v2f d; asm("v_pk_mul_f32 %0, %1, %2" : "=v"(d) : "v"(a), "v"(b)); return d;
}

// ---- DPP wave-64 reduction steps (idempotent ops -> full masks safe) ----
template <int CTRL>
__device__ __forceinline__ float dpp_fmax_step(float x) {
    int xi = __float_as_int(x);
    int yi = __builtin_amdgcn_update_dpp(xi, xi, CTRL, 0xf, 0xf, false);
    return fmaxf(x, __int_as_float(yi));
}
template <int CTRL>
__device__ __forceinline__ unsigned dpp_umin_step(unsigned x) {
    int xi = (int)x;
    unsigned y = (unsigned)__builtin_amdgcn_update_dpp(xi, xi, CTRL, 0xf, 0xf, false);
    return y < x ? y : x;
}
__device__ __forceinline__ unsigned wave_umin(unsigned x) {
    x = dpp_umin_step<0x111>(x);
    x = dpp_umin_step<0x112>(x);
    x = dpp_umin_step<0x114>(x);
    x = dpp_umin_step<0x118>(x);
    x = dpp_umin_step<0x142>(x);
    x = dpp_umin_step<0x143>(x);
    return (unsigned)__builtin_amdgcn_readlane((int)x, 63);
}

// ---------------------------------------------------------------------------
// Kernel 1: furthest point sampling with x-slab wave pruning (R7) plus:
// R8a — picks buffered in a 512-entry LDS ring, flushed to global coalesced
//        once per 512 iters (removes the per-iter global-store vmcnt drain
//        that __syncthreads forces onto the critical path).
// R8b — winner record s_cq as float4 (single ds_read_b128 post-barrier2).
// ---------------------------------------------------------------------------
__global__ __launch_bounds__(1024) void fps_kernel(const float* __restrict__ p,
                                                   float* __restrict__ out) {
#pragma clang fp contract(off)
    const int t = threadIdx.x;
    const int lane = t & 63, wv = t >> 6;
    __shared__ char smem[147456];                      // keys[16384] then s_xy4[1024*9]
    __shared__ float s_pick[512 * 3];                  // pick ring (6 KB)
    __shared__ float s_wmax[2][16];
    __shared__ float4 s_cq4[16];
    __shared__ ull s_key[2];

    ull* keys = (ull*)smem;
    float4* s_xy4 = (float4*)smem;

    // ---- Phase A: bitonic sort by x (keys unique via idx bits) ----
    for (int u = 0; u < 16; ++u) {
        const int j = u * 1024 + t;
        keys[j] = ((ull)__float_as_uint(p[3 * j]) << 32) | (unsigned)j;
    }
    __syncthreads();
    for (int k = 2; k <= N_PTS; k <<= 1) {
        for (int j = k >> 1; j > 0; j >>= 1) {
            for (int e = 0; e < 8; ++e) {
                const int c = e * 1024 + t;
                const int i1 = 2 * c - (c & (j - 1));
                const int i2 = i1 + j;
                const ull a = keys[i1], b = keys[i2];
                const bool up = ((i1 & k) == 0);
                if ((a > b) == up) { keys[i1] = b; keys[i2] = a; }
            }
            __syncthreads();
        }
    }

    // read own 16 sorted keys -> packed original indices (8 regs)
    unsigned opk[8];
#pragma unroll
    for (int u = 0; u < 8; ++u) {
        const ull a = keys[t * 16 + 2 * u];
        const ull b = keys[t * 16 + 2 * u + 1];
        opk[u] = ((unsigned)a & 0xffffu) | (((unsigned)b & 0xffffu) << 16);
    }
    __syncthreads();                                   // all key reads done before overwrite

    // ---- gather coords, build LDS xy ({x0,x1,y0,y1}) + reg z/d2, init bv ----
    v2f zp[8], d2[8];
    const float q0x = p[0], q0y = p[1], q0z = p[2];
    float bv = -1.0f;
    float xf = 0.0f, xl = 0.0f;
#pragma unroll
    for (int u = 0; u < 8; ++u) {
        const int o0 = (int)(opk[u] & 0xffffu), o1 = (int)(opk[u] >> 16);
        const float x0 = p[3 * o0], y0 = p[3 * o0 + 1], z0 = p[3 * o0 + 2];
        const float x1 = p[3 * o1], y1 = p[3 * o1 + 1], z1 = p[3 * o1 + 2];
        s_xy4[t * 9 + u] = make_float4(x0, x1, y0, y1);
        zp[u] = (v2f){z0, z1};
        d2[u] = (v2f){dist2_exact(x0, y0, z0, q0x, q0y, q0z),
                      dist2_exact(x1, y1, z1, q0x, q0y, q0z)};
        bv = fmaxf(bv, fmaxf(d2[u].x, d2[u].y));
        if (u == 0) xf = x0;
        if (u == 7) xl = x1;
    }
    // wave x-slab bounds (sorted ascending: lane0/slot0 = min, lane63/slot15 = max)
    const float wxmin = __int_as_float(__builtin_amdgcn_readlane(__float_as_int(xf), 0));
    const float wxmax = __int_as_float(__builtin_amdgcn_readlane(__float_as_int(xl), 63));
    const float cx = 0.5f * (wxmin + wxmax);
    const float hw_safe = 0.5f * (wxmax - wxmin) + 1e-5f;   // slack >> fp32 rounding

    if (t == 0) {
        s_pick[0] = q0x; s_pick[1] = q0y; s_pick[2] = q0z;  // pick 0 into ring
        s_key[0] = 0ull; s_key[1] = 0ull;
    }

    for (int i = 1; i < M_PTS; ++i) {
        const int par = i & 1;
        // per-wave max of bv (6 DPP steps), lane63 -> sgpr broadcast
        float wval = bv;
        wval = dpp_fmax_step<0x111>(wval);
        wval = dpp_fmax_step<0x112>(wval);
        wval = dpp_fmax_step<0x114>(wval);
        wval = dpp_fmax_step<0x118>(wval);
        wval = dpp_fmax_step<0x142>(wval);
        wval = dpp_fmax_step<0x143>(wval);
        const float wmax_u = __int_as_float(__builtin_amdgcn_readlane(__float_as_int(wval), 63));
        if (lane == 63) s_wmax[par][wv] = wval;
        if (t == 0) s_key[1 - par] = 0ull;             // reset for NEXT iteration
        __syncthreads();                               // barrier 1

        // ring flush: once per 512 iters, all threads store the previous block
        // coalesced. Ring writes are >=1 barrier old -> visible. Store drain
        // happens at barrier2 of THIS iter only (8 times total).
        if ((i & 511) == 0) {
            const int base3 = (i - 512) * 3;
            out[base3 + t] = s_pick[t];
            if (t < 512) out[base3 + 1024 + t] = s_pick[1024 + t];
        }

        // cross-wave value max: 16 floats, 4 row_shr steps within 16-lane rows
        float cv = s_wmax[par][lane & 15];
        cv = dpp_fmax_step<0x111>(cv);
        cv = dpp_fmax_step<0x112>(cv);
        cv = dpp_fmax_step<0x114>(cv);
        cv = dpp_fmax_step<0x118>(cv);
        const float vmax = __int_as_float(__builtin_amdgcn_readlane(__float_as_int(cv), 63));

        // lazy resolution: only wave(s) holding the global max. Tie-break on
        // ORIGINAL index. Register arrays indexed only by unrolled constants.
        if (wmax_u == vmax) {
            unsigned borig = 0xffffu;
            unsigned bslot = 0;
            float cqz = 0.0f;
#pragma unroll
            for (int u = 0; u < 16; ++u) {
                const float dv = (u & 1) ? d2[u >> 1].y : d2[u >> 1].x;
                const unsigned ou = (u & 1) ? (opk[u >> 1] >> 16) : (opk[u >> 1] & 0xffffu);
                if (dv == vmax && ou < borig) {
                    borig = ou;
                    bslot = (unsigned)u;
                    cqz = (u & 1) ? zp[u >> 1].y : zp[u >> 1].x;
                }
            }
            const unsigned wmin = wave_umin((borig << 6) | (unsigned)lane);
            if ((wmin & 63u) == (unsigned)lane && borig != 0xffffu) {
                // winner lane: xy from own LDS region (runtime LDS addr is fine)
                const float4 xy = s_xy4[t * 9 + (bslot >> 1)];
                const float qx = (bslot & 1) ? xy.y : xy.x;
                const float qy = (bslot & 1) ? xy.w : xy.z;
                s_cq4[wv] = make_float4(qx, qy, cqz, 0.0f);
                const ull key = ((ull)__float_as_uint(vmax) << 32) |
                                (ull)(~((borig << 4) | (unsigned)wv));
                atomicMax(&s_key[par], key);
            }
        }
        __syncthreads();                               // barrier 2

        const unsigned packed = ~((unsigned)s_key[par]);
        const int wwin = (int)(packed & 15u);
        const float4 cq = s_cq4[wwin];                 // one ds_read_b128
        float qx = cq.x, qy = cq.y, qz = cq.z;
        if (t == 0) {                                  // pick -> LDS ring only
            const int s3 = (i & 511) * 3;
            s_pick[s3] = qx; s_pick[s3 + 1] = qy; s_pick[s3 + 2] = qz;
        }
        qx = __int_as_float(__builtin_amdgcn_readfirstlane(__float_as_int(qx)));
        qy = __int_as_float(__builtin_amdgcn_readfirstlane(__float_as_int(qy)));
        qz = __int_as_float(__builtin_amdgcn_readfirstlane(__float_as_int(qz)));

        // ---- wave-level slab prune: skip update iff provably all no-ops ----
        const float dxq = fabsf(qx - cx);
        bool active = true;
        if (dxq > hw_safe) {
            const float lb = dxq - hw_safe;            // conservative lower bound
            active = (lb * lb <= wmax_u);
        }
        if (active) {
            const v2f nqx2 = (v2f){-qx, -qx};
            const v2f nqy2 = (v2f){-qy, -qy};
            const v2f nqz2 = (v2f){-qz, -qz};
            bv = -1.0f;
#pragma unroll
            for (int u = 0; u < 8; ++u) {
                const float4 xy = s_xy4[t * 9 + u];
                const v2f xp = (v2f){xy.x, xy.y};      // {x0,x1} — no repack
                const v2f yp = (v2f){xy.z, xy.w};      // {y0,y1}
                const v2f dx = pk_add(xp, nqx2);       // exact x - qx
                const v2f dy = pk_add(yp, nqy2);
                const v2f dz = pk_add(zp[u], nqz2);
                const v2f m1 = pk_mul(dx, dx);
                const v2f m2 = pk_mul(dy, dy);
                const v2f m3 = pk_mul(dz, dz);
                const v2f s = pk_add(pk_add(m1, m2), m3);  // ((x²+y²)+z²) exact order
                d2[u] = __builtin_elementwise_min(d2[u], s);
                bv = fmaxf(bv, fmaxf(d2[u].x, d2[u].y));
            }
        }
    }

    // final flush: picks 3584..4095 (ring-aligned) + n_o scalar
    __syncthreads();
    {
        const int base3 = 3584 * 3;
        out[base3 + t] = s_pick[t];
        if (t < 512) out[base3 + 1024 + t] = s_pick[1024 + t];
        if (t == 0) out[12288 + 786432] = 4096.0f;
    }
}

// ---------------------------------------------------------------------------
// Kernel 2: kNN (k=16) of each n_p among p. One wave per query, per-lane sorted
// top-16 in registers, lexicographic (d, idx) wave merge (matches top_k ties).
// ---------------------------------------------------------------------------
__global__ __launch_bounds__(256) void knn_kernel(const float* __restrict__ p,
                                                  const float* __restrict__ np_,
                                                  int* __restrict__ nn) {
    const int lane = threadIdx.x & 63;
    const int m = (blockIdx.x * 256 + threadIdx.x) >> 6;
    if (m >= M_PTS) return;

    const float qx = np_[3 * m], qy = np_[3 * m + 1], qz = np_[3 * m + 2];
    const float qq = __fadd_rn(__fadd_rn(__fmul_rn(qx, qx), __fmul_rn(qy, qy)),
                               __fmul_rn(qz, qz));
    float D[16]; int I[16];
#pragma unroll
    for (int s = 0; s < 16; ++s) { D[s] = FLT_MAX; I[s] = 0x7fffffff; }

    for (int c = 0; c < N_PTS / 64; ++c) {
        const int j = c * 64 + lane;
        const float px = p[3 * j], py = p[3 * j + 1], pz = p[3 * j + 2];
        const float pp = __fadd_rn(__fadd_rn(__fmul_rn(px, px), __fmul_rn(py, py)),
                                   __fmul_rn(pz, pz));
        const float qp = __fadd_rn(__fadd_rn(__fmul_rn(qx, px), __fmul_rn(qy, py)),
                                   __fmul_rn(qz, pz));
        const float d = __fadd_rn(__fsub_rn(qq, __fmul_rn(2.0f, qp)), pp);
        if (d < D[15]) {
            D[15] = d; I[15] = j;
#pragma unroll
            for (int s = 15; s > 0; --s) {
                if (D[s] < D[s - 1]) {
                    float tf = D[s]; D[s] = D[s - 1]; D[s - 1] = tf;
                    int   ti = I[s]; I[s] = I[s - 1]; I[s - 1] = ti;
                }
            }
        }
    }

    int myout = 0;
    for (int r = 0; r < 16; ++r) {
        float v = D[0]; int ix = I[0]; int bl = lane;
#pragma unroll
        for (int off = 1; off < 64; off <<= 1) {
            float ov = __shfl_xor(v, off);
            int   oi = __shfl_xor(ix, off);
            int   ol = __shfl_xor(bl, off);
            if (ov < v || (ov == v && oi < ix)) { v = ov; ix = oi; bl = ol; }
        }
        if (lane == bl) {
#pragma unroll
            for (int s = 0; s < 15; ++s) { D[s] = D[s + 1]; I[s] = I[s + 1]; }
            D[15] = FLT_MAX; I[15] = 0x7fffffff;
        }
        if (lane == r) myout = ix;
    }
    if (lane < K_NN) nn[m * K_NN + lane] = myout;
}

// ---------------------------------------------------------------------------
// Kernel 3: grouped VNLinearLeakyReLU + mean over nsample.
// One block per query m. W_feat/W_dir staged transposed in LDS; thread (o,i)
// accumulates over k. out layout (Cout,3,M): out[(o*3+i)*M + m].
// ---------------------------------------------------------------------------
__global__ __launch_bounds__(256) void vn_kernel(const float* __restrict__ x,
                                                 const float* __restrict__ Wf,
                                                 const float* __restrict__ Wd,
                                                 const int* __restrict__ nn,
                                                 float* __restrict__ out) {
    __shared__ float sWf[CIN * COUT];
    __shared__ float sWd[CIN * COUT];
    __shared__ float sg[CIN * 3];
    __shared__ float sq[COUT * 3];
    __shared__ float sd[COUT * 3];
    __shared__ float sf[COUT];

    const int m = blockIdx.x;
    const int tid = threadIdx.x;
    for (int u = tid; u < CIN * COUT; u += 256) {
        const int o = u >> 6, c = u & 63;
        sWf[c * 64 + o] = Wf[u];
        sWd[c * 64 + o] = Wd[u];
    }
    const int o = tid & 63, i = tid >> 6;
    const bool active = tid < 192;
    float acc = 0.0f;

    for (int k = 0; k < K_NN; ++k) {
        __syncthreads();
        const int j = nn[m * K_NN + k];
        if (tid < 192) sg[tid] = x[j * 192 + tid];
        __syncthreads();
        float qv = 0.0f, dv = 0.0f;
        if (active) {
#pragma unroll
            for (int c = 0; c < CIN; ++c) {
                const float g = sg[c * 3 + i];
                qv = fmaf(sWf[c * 64 + o], g, qv);
                dv = fmaf(sWd[c * 64 + o], g, dv);
            }
            sq[o * 3 + i] = qv;
            sd[o * 3 + i] = dv;
        }
        __syncthreads();
        if (tid < 64) {
            const float d0 = sd[tid * 3], d1 = sd[tid * 3 + 1], d2v = sd[tid * 3 + 2];
            const float q0 = sq[tid * 3], q1 = sq[tid * 3 + 1], q2 = sq[tid * 3 + 2];
            const float dot = q0 * d0 + q1 * d1 + q2 * d2v;
            const float dns = d0 * d0 + d1 * d1 + d2v * d2v + 1e-6f;
            sf[tid] = (dot >= 0.0f) ? 0.0f : 0.8f * (dot / dns);
        }
        __syncthreads();
        if (active) acc += qv - sf[o] * dv;
    }
    if (active) out[(o * 3 + i) * M_PTS + m] = acc * 0.0625f;
}

// ---------------------------------------------------------------------------
extern "C" void kernel_launch(void* const* d_in, const int* in_sizes, int n_in,
                              void* d_out, int out_size, void* d_ws, size_t ws_size,
                              hipStream_t stream) {
    const float* p  = (const float*)d_in[0];
    const float* x  = (const float*)d_in[1];
    const float* Wf = (const float*)d_in[2];
    const float* Wd = (const float*)d_in[3];
    float* out = (float*)d_out;
    int* nn = (int*)d_ws;

    fps_kernel<<<1, 1024, 0, stream>>>(p, out);
    knn_kernel<<<M_PTS / 4, 256, 0, stream>>>(p, out, nn);
    vn_kernel<<<M_PTS, 256, 0, stream>>>(x, Wf, Wd, nn, out + 12288);
}

// Round 9
// 5710.345 us; speedup vs baseline: 1.0576x; 1.0576x over previous
//
#include <hip/hip_runtime.h>
#include <float.h>

#define N_PTS 16384
#define M_PTS 4096
#define K_NN  16
#define CIN   64
#define COUT  64

typedef float v2f __attribute__((ext_vector_type(2)));
typedef unsigned long long ull;

// Exact f32 rounding to match numpy/jax: ((dx*dx + dy*dy) + dz*dz), no fma contraction.
__device__ __forceinline__ float dist2_exact(float ax, float ay, float az,
                                             float bx, float by, float bz) {
    float dx = __fsub_rn(ax, bx);
    float dy = __fsub_rn(ay, by);
    float dz = __fsub_rn(az, bz);
    return __fadd_rn(__fadd_rn(__fmul_rn(dx, dx), __fmul_rn(dy, dy)), __fmul_rn(dz, dz));
}

// Packed f32 ops via inline asm (v2f codegen otherwise scalarizes — R6 evidence).
__device__ __forceinline__ v2f pk_add(v2f a, v2f b) {
    v2f d; asm("v_pk_add_f32 %0, %1, %2" : "=v"(d) : "v"(a), "v"(b)); return d;
}
__device__ __forceinline__ v2f pk_mul(v2f a, v2f b) {
    v2f d; asm("v_pk_mul_f32 %0, %1, %2" : "=v"(d) : "v"(a), "v"(b)); return d;
}

// ---- DPP wave-64 reduction steps (idempotent ops -> full masks safe) ----
template <int CTRL>
__device__ __forceinline__ float dpp_fmax_step(float x) {
    int xi = __float_as_int(x);
    int yi = __builtin_amdgcn_update_dpp(xi, xi, CTRL, 0xf, 0xf, false);
    return fmaxf(x, __int_as_float(yi));
}
template <int CTRL>
__device__ __forceinline__ unsigned dpp_umin_step(unsigned x) {
    int xi = (int)x;
    unsigned y = (unsigned)__builtin_amdgcn_update_dpp(xi, xi, CTRL, 0xf, 0xf, false);
    return y < x ? y : x;
}
template <int CTRL>
__device__ __forceinline__ ull dpp_u64max_step(ull x) {
    int lo = (int)(unsigned)x;
    int hi = (int)(unsigned)(x >> 32);
    unsigned olo = (unsigned)__builtin_amdgcn_update_dpp(lo, lo, CTRL, 0xf, 0xf, false);
    unsigned ohi = (unsigned)__builtin_amdgcn_update_dpp(hi, hi, CTRL, 0xf, 0xf, false);
    ull o = ((ull)ohi << 32) | (ull)olo;
    return o > x ? o : x;
}
__device__ __forceinline__ unsigned wave_umin(unsigned x) {
    x = dpp_umin_step<0x111>(x);
    x = dpp_umin_step<0x112>(x);
    x = dpp_umin_step<0x114>(x);
    x = dpp_umin_step<0x118>(x);
    x = dpp_umin_step<0x142>(x);
    x = dpp_umin_step<0x143>(x);
    return (unsigned)__builtin_amdgcn_readlane((int)x, 63);
}

// Per-wave record extraction: wave max of d2 -> (val, qx, qy, qz, orig) in SGPRs.
// Scans use ONLY compile-time register indices; xy comes from LDS (runtime ok).
#define EXTRACT_RECORD()                                                          \
    {                                                                             \
        float _w = bv;                                                            \
        _w = dpp_fmax_step<0x111>(_w);                                            \
        _w = dpp_fmax_step<0x112>(_w);                                            \
        _w = dpp_fmax_step<0x114>(_w);                                            \
        _w = dpp_fmax_step<0x118>(_w);                                            \
        _w = dpp_fmax_step<0x142>(_w);                                            \
        _w = dpp_fmax_step<0x143>(_w);                                            \
        my_wval = __int_as_float(__builtin_amdgcn_readlane(__float_as_int(_w), 63)); \
        unsigned _kk = 0xffffffffu;                                               \
        float _cz = 0.0f;                                                         \
        _Pragma("unroll")                                                         \
        for (int _u = 0; _u < 16; ++_u) {                                         \
            const float _dv = (_u & 1) ? d2[_u >> 1].y : d2[_u >> 1].x;           \
            const unsigned _og = (_u & 1) ? (opk[_u >> 1] >> 16)                  \
                                          : (opk[_u >> 1] & 0xffffu);             \
            const unsigned _ky = (_og << 4) | (unsigned)_u;                       \
            const unsigned _uk = (_dv == my_wval) ? _ky : 0xffffffffu;            \
            if (_uk < _kk) {                                                      \
                _kk = _uk;                                                        \
                _cz = (_u & 1) ? zp[_u >> 1].y : zp[_u >> 1].x;                   \
            }                                                                     \
        }                                                                         \
        const unsigned _wkk = wave_umin(_kk);                                     \
        const ull _m = __ballot(_kk == _wkk);                                     \
        const int _wl = (int)__builtin_ctzll(_m);                                 \
        my_orig = _wkk >> 4;                                                      \
        const int _slot = (int)(_wkk & 15u);                                      \
        const int _wt = wv * 64 + _wl;                                            \
        const float4 _xy = s_xy4[_wt * 9 + (_slot >> 1)];                         \
        const float _qx = (_slot & 1) ? _xy.y : _xy.x;                            \
        const float _qy = (_slot & 1) ? _xy.w : _xy.z;                            \
        my_qx = __int_as_float(__builtin_amdgcn_readfirstlane(__float_as_int(_qx))); \
        my_qy = __int_as_float(__builtin_amdgcn_readfirstlane(__float_as_int(_qy))); \
        my_qz = __int_as_float(__builtin_amdgcn_readlane(__float_as_int(_cz), _wl)); \
    }

// ---------------------------------------------------------------------------
// Kernel 1: furthest point sampling, single-barrier persistent-record design.
// Per wave: persistent record {max d2, coords, orig} in parity LDS buffers.
// Per iter: barrier -> read 16 records -> u64 DPP max (exact tie-break via
// ~orig, no atomics) -> winner coords via ballot+readlane -> x-slab prune ->
// active waves update d2 + re-extract record; all waves copy-forward (SGPRs).
// Picks buffered in a 1024-entry LDS ring (race-free 512-block flushes).
// ---------------------------------------------------------------------------
__global__ __launch_bounds__(1024) void fps_kernel(const float* __restrict__ p,
                                                   float* __restrict__ out) {
#pragma clang fp contract(off)
    const int t = threadIdx.x;
    const int lane = t & 63, wv = t >> 6;
    __shared__ char smem[147456];                      // keys[16384] then s_xy4[1024*9]
    __shared__ float s_pick[1024 * 3];                 // pick ring (12 KB)
    __shared__ float4 s_recf[2][16];                   // {val, qx, qy, qz}
    __shared__ unsigned s_reco[2][16];                 // orig

    ull* keys = (ull*)smem;
    float4* s_xy4 = (float4*)smem;

    // ---- Phase A: bitonic sort by x (keys unique via idx bits) ----
    for (int u = 0; u < 16; ++u) {
        const int j = u * 1024 + t;
        keys[j] = ((ull)__float_as_uint(p[3 * j]) << 32) | (unsigned)j;
    }
    __syncthreads();
    for (int k = 2; k <= N_PTS; k <<= 1) {
        for (int j = k >> 1; j > 0; j >>= 1) {
            for (int e = 0; e < 8; ++e) {
                const int c = e * 1024 + t;
                const int i1 = 2 * c - (c & (j - 1));
                const int i2 = i1 + j;
                const ull a = keys[i1], b = keys[i2];
                const bool up = ((i1 & k) == 0);
                if ((a > b) == up) { keys[i1] = b; keys[i2] = a; }
            }
            __syncthreads();
        }
    }

    // read own 16 sorted keys -> packed original indices (8 regs)
    unsigned opk[8];
#pragma unroll
    for (int u = 0; u < 8; ++u) {
        const ull a = keys[t * 16 + 2 * u];
        const ull b = keys[t * 16 + 2 * u + 1];
        opk[u] = ((unsigned)a & 0xffffu) | (((unsigned)b & 0xffffu) << 16);
    }
    __syncthreads();                                   // all key reads done before overwrite

    // ---- gather coords, build LDS xy ({x0,x1,y0,y1}) + reg z/d2, init bv ----
    v2f zp[8], d2[8];
    const float q0x = p[0], q0y = p[1], q0z = p[2];
    float bv = -1.0f;
    float xf = 0.0f, xl = 0.0f;
#pragma unroll
    for (int u = 0; u < 8; ++u) {
        const int o0 = (int)(opk[u] & 0xffffu), o1 = (int)(opk[u] >> 16);
        const float x0 = p[3 * o0], y0 = p[3 * o0 + 1], z0 = p[3 * o0 + 2];
        const float x1 = p[3 * o1], y1 = p[3 * o1 + 1], z1 = p[3 * o1 + 2];
        s_xy4[t * 9 + u] = make_float4(x0, x1, y0, y1);
        zp[u] = (v2f){z0, z1};
        d2[u] = (v2f){dist2_exact(x0, y0, z0, q0x, q0y, q0z),
                      dist2_exact(x1, y1, z1, q0x, q0y, q0z)};
        bv = fmaxf(bv, fmaxf(d2[u].x, d2[u].y));
        if (u == 0) xf = x0;
        if (u == 7) xl = x1;
    }
    // wave x-slab bounds (sorted ascending: lane0/slot0 = min, lane63/slot15 = max)
    const float wxmin = __int_as_float(__builtin_amdgcn_readlane(__float_as_int(xf), 0));
    const float wxmax = __int_as_float(__builtin_amdgcn_readlane(__float_as_int(xl), 63));
    const float cx = 0.5f * (wxmin + wxmax);
    const float hw_safe = 0.5f * (wxmax - wxmin) + 1e-5f;   // slack >> fp32 rounding

    // ---- initial per-wave record -> rec[1] (read at iter 1) ----
    float my_wval, my_qx, my_qy, my_qz;
    unsigned my_orig;
    EXTRACT_RECORD();
    if (lane == 0) {
        s_recf[1][wv] = make_float4(my_wval, my_qx, my_qy, my_qz);
        s_reco[1][wv] = my_orig;
    }
    if (t == 0) { s_pick[0] = q0x; s_pick[1] = q0y; s_pick[2] = q0z; }

    for (int i = 1; i < M_PTS; ++i) {
        const int par = i & 1;
        __syncthreads();                               // the ONE barrier per iteration

        // ring flush: once per 512 iters, previous 512-block (other ring half;
        // this iter's pick goes to the half not being read -> race-free).
        if ((i & 511) == 0) {
            const int b = (i - 512) & 1023;
            const int base3 = (i - 512) * 3;
            out[base3 + t] = s_pick[b * 3 + t];
            if (t < 512) out[base3 + 1024 + t] = s_pick[b * 3 + 1024 + t];
        }

        // global winner from the 16 records: u64 key = (val_bits<<32 | ~orig)
        const int r = lane & 15;
        const float4 rf = s_recf[par][r];
        const unsigned ro = s_reco[par][r];
        ull key = ((ull)__float_as_uint(rf.x) << 32) | (ull)(~ro);
        ull red = key;
        red = dpp_u64max_step<0x111>(red);
        red = dpp_u64max_step<0x112>(red);
        red = dpp_u64max_step<0x114>(red);
        red = dpp_u64max_step<0x118>(red);
        const unsigned wlo = (unsigned)__builtin_amdgcn_readlane((int)(unsigned)red, 63);
        const unsigned whi = (unsigned)__builtin_amdgcn_readlane((int)(unsigned)(red >> 32), 63);
        const ull wk = ((ull)whi << 32) | (ull)wlo;
        const ull hm = __ballot(key == wk);
        const int hl = (int)__builtin_ctzll(hm);       // a lane holding the winner record
        const float qx = __int_as_float(__builtin_amdgcn_readlane(__float_as_int(rf.y), hl));
        const float qy = __int_as_float(__builtin_amdgcn_readlane(__float_as_int(rf.z), hl));
        const float qz = __int_as_float(__builtin_amdgcn_readlane(__float_as_int(rf.w), hl));
        if (t == 0) {
            const int s3 = (i & 1023) * 3;
            s_pick[s3] = qx; s_pick[s3 + 1] = qy; s_pick[s3 + 2] = qz;
        }

        // ---- wave-level slab prune: skip update iff provably all no-ops ----
        const float dxq = fabsf(qx - cx);
        bool active = true;
        if (dxq > hw_safe) {
            const float lb = dxq - hw_safe;            // conservative lower bound
            active = (lb * lb <= my_wval);
        }
        if (active) {
            const v2f nqx2 = (v2f){-qx, -qx};
            const v2f nqy2 = (v2f){-qy, -qy};
            const v2f nqz2 = (v2f){-qz, -qz};
            bv = -1.0f;
#pragma unroll
            for (int u = 0; u < 8; ++u) {
                const float4 xy = s_xy4[t * 9 + u];
                const v2f xp = (v2f){xy.x, xy.y};      // {x0,x1}
                const v2f yp = (v2f){xy.z, xy.w};      // {y0,y1}
                const v2f dx = pk_add(xp, nqx2);       // exact x - qx
                const v2f dy = pk_add(yp, nqy2);
                const v2f dz = pk_add(zp[u], nqz2);
                const v2f m1 = pk_mul(dx, dx);
                const v2f m2 = pk_mul(dy, dy);
                const v2f m3 = pk_mul(dz, dz);
                const v2f s = pk_add(pk_add(m1, m2), m3);  // ((x²+y²)+z²) exact order
                d2[u] = __builtin_elementwise_min(d2[u], s);
                bv = fmaxf(bv, fmaxf(d2[u].x, d2[u].y));
            }
            EXTRACT_RECORD();                          // refresh record (SGPRs)
        }
        // every wave posts its (possibly unchanged) record for the next iter
        if (lane == 0) {
            s_recf[1 - par][wv] = make_float4(my_wval, my_qx, my_qy, my_qz);
            s_reco[1 - par][wv] = my_orig;
        }
    }

    // final flush: picks 3584..4095 (ring half b=512) + n_o scalar
    __syncthreads();
    {
        const int base3 = 3584 * 3;
        const int b3 = 512 * 3;
        out[base3 + t] = s_pick[b3 + t];
        if (t < 512) out[base3 + 1024 + t] = s_pick[b3 + 1024 + t];
        if (t == 0) out[12288 + 786432] = 4096.0f;
    }
}

// ---------------------------------------------------------------------------
// Kernel 2: kNN (k=16) of each n_p among p. One wave per query, per-lane sorted
// top-16 in registers, lexicographic (d, idx) wave merge (matches top_k ties).
// ---------------------------------------------------------------------------
__global__ __launch_bounds__(256) void knn_kernel(const float* __restrict__ p,
                                                  const float* __restrict__ np_,
                                                  int* __restrict__ nn) {
    const int lane = threadIdx.x & 63;
    const int m = (blockIdx.x * 256 + threadIdx.x) >> 6;
    if (m >= M_PTS) return;

    const float qx = np_[3 * m], qy = np_[3 * m + 1], qz = np_[3 * m + 2];
    const float qq = __fadd_rn(__fadd_rn(__fmul_rn(qx, qx), __fmul_rn(qy, qy)),
                               __fmul_rn(qz, qz));
    float D[16]; int I[16];
#pragma unroll
    for (int s = 0; s < 16; ++s) { D[s] = FLT_MAX; I[s] = 0x7fffffff; }

    for (int c = 0; c < N_PTS / 64; ++c) {
        const int j = c * 64 + lane;
        const float px = p[3 * j], py = p[3 * j + 1], pz = p[3 * j + 2];
        const float pp = __fadd_rn(__fadd_rn(__fmul_rn(px, px), __fmul_rn(py, py)),
                                   __fmul_rn(pz, pz));
        const float qp = __fadd_rn(__fadd_rn(__fmul_rn(qx, px), __fmul_rn(qy, py)),
                                   __fmul_rn(qz, pz));
        const float d = __fadd_rn(__fsub_rn(qq, __fmul_rn(2.0f, qp)), pp);
        if (d < D[15]) {
            D[15] = d; I[15] = j;
#pragma unroll
            for (int s = 15; s > 0; --s) {
                if (D[s] < D[s - 1]) {
                    float tf = D[s]; D[s] = D[s - 1]; D[s - 1] = tf;
                    int   ti = I[s]; I[s] = I[s - 1]; I[s - 1] = ti;
                }
            }
        }
    }

    int myout = 0;
    for (int r = 0; r < 16; ++r) {
        float v = D[0]; int ix = I[0]; int bl = lane;
#pragma unroll
        for (int off = 1; off < 64; off <<= 1) {
            float ov = __shfl_xor(v, off);
            int   oi = __shfl_xor(ix, off);
            int   ol = __shfl_xor(bl, off);
            if (ov < v || (ov == v && oi < ix)) { v = ov; ix = oi; bl = ol; }
        }
        if (lane == bl) {
#pragma unroll
            for (int s = 0; s < 15; ++s) { D[s] = D[s + 1]; I[s] = I[s + 1]; }
            D[15] = FLT_MAX; I[15] = 0x7fffffff;
        }
        if (lane == r) myout = ix;
    }
    if (lane < K_NN) nn[m * K_NN + lane] = myout;
}

// ---------------------------------------------------------------------------
// Kernel 3: grouped VNLinearLeakyReLU + mean over nsample.
// One block per query m. W_feat/W_dir staged transposed in LDS; thread (o,i)
// accumulates over k. out layout (Cout,3,M): out[(o*3+i)*M + m].
// ---------------------------------------------------------------------------
__global__ __launch_bounds__(256) void vn_kernel(const float* __restrict__ x,
                                                 const float* __restrict__ Wf,
                                                 const float* __restrict__ Wd,
                                                 const int* __restrict__ nn,
                                                 float* __restrict__ out) {
    __shared__ float sWf[CIN * COUT];
    __shared__ float sWd[CIN * COUT];
    __shared__ float sg[CIN * 3];
    __shared__ float sq[COUT * 3];
    __shared__ float sd[COUT * 3];
    __shared__ float sf[COUT];

    const int m = blockIdx.x;
    const int tid = threadIdx.x;
    for (int u = tid; u < CIN * COUT; u += 256) {
        const int o = u >> 6, c = u & 63;
        sWf[c * 64 + o] = Wf[u];
        sWd[c * 64 + o] = Wd[u];
    }
    const int o = tid & 63, i = tid >> 6;
    const bool active = tid < 192;
    float acc = 0.0f;

    for (int k = 0; k < K_NN; ++k) {
        __syncthreads();
        const int j = nn[m * K_NN + k];
        if (tid < 192) sg[tid] = x[j * 192 + tid];
        __syncthreads();
        float qv = 0.0f, dv = 0.0f;
        if (active) {
#pragma unroll
            for (int c = 0; c < CIN; ++c) {
                const float g = sg[c * 3 + i];
                qv = fmaf(sWf[c * 64 + o], g, qv);
                dv = fmaf(sWd[c * 64 + o], g, dv);
            }
            sq[o * 3 + i] = qv;
            sd[o * 3 + i] = dv;
        }
        __syncthreads();
        if (tid < 64) {
            const float d0 = sd[tid * 3], d1 = sd[tid * 3 + 1], d2v = sd[tid * 3 + 2];
            const float q0 = sq[tid * 3], q1 = sq[tid * 3 + 1], q2 = sq[tid * 3 + 2];
            const float dot = q0 * d0 + q1 * d1 + q2 * d2v;
            const float dns = d0 * d0 + d1 * d1 + d2v * d2v + 1e-6f;
            sf[tid] = (dot >= 0.0f) ? 0.0f : 0.8f * (dot / dns);
        }
        __syncthreads();
        if (active) acc += qv - sf[o] * dv;
    }
    if (active) out[(o * 3 + i) * M_PTS + m] = acc * 0.0625f;
}

// ---------------------------------------------------------------------------
extern "C" void kernel_launch(void* const* d_in, const int* in_sizes, int n_in,
                              void* d_out, int out_size, void* d_ws, size_t ws_size,
                              hipStream_t stream) {
    const float* p  = (const float*)d_in[0];
    const float* x  = (const float*)d_in[1];
    const float* Wf = (const float*)d_in[2];
    const float* Wd = (const float*)d_in[3];
    float* out = (float*)d_out;
    int* nn = (int*)d_ws;

    fps_kernel<<<1, 1024, 0, stream>>>(p, out);
    knn_kernel<<<M_PTS / 4, 256, 0, stream>>>(p, out, nn);
    vn_kernel<<<M_PTS, 256, 0, stream>>>(x, Wf, Wd, nn, out + 12288);
}